// Round 5
// baseline (1322.721 us; speedup 1.0000x reference)
//
#include <hip/hip_runtime.h>
#include <hip/hip_bf16.h>

// out[b] = mean_x( 0.5 - 0.5*tanh((x - bins[b]) * 2/bw) ), bw = 0.0625,
//          bins[b] = -2 + bw*b, b in [0,64)
// t = (x+2)*16 (bin coord); element contribution to bin b = sigma(4(b-t)),
// saturating to {0,1} for |b-t| >= 5. Fine histogram of t (cell = 1/32 bin,
// t in [-5,69), 2368 cells) is a sufficient statistic (quant bias ~6e-5).
//
// R2-R4 lesson: scattered LDS atomics retire ~1 lane/cyc/CU -> 67.1M atomics
// = 109 us floor on the LDS pipe alone (measured, grid/unroll-insensitive).
// Fix: split scatter across the TWO independent pipes — waves 0,1 use LDS
// atomics; waves 2,3 use fire-and-forget global_atomic_add into 256
// privatized L2-resident copies (copy-major, 9.5 KB each). Each pipe gets
// 33.5M atomics (~55 us), overlapped. LDS hist is flushed into the copies.
// Then: collapse (sum 256 copies) -> windowed-sigmoid kernel -> out.

#define DLOG   5                    // cells per bin = 32
#define MCELLS (74 << DLOG)         // 2368 cells, t in [-5, 69)
#define NCOPIES 256                 // 256 * 9.47 KB = 2.42 MB, L2-resident
#define HB 2048
#define HT 256

__global__ void __launch_bounds__(HT)
hist_kernel(const float* __restrict__ x, unsigned* __restrict__ ghist, int n)
{
    __shared__ unsigned lh[MCELLS];             // 9.47 KB
    const int tid = threadIdx.x;
    for (int i = tid; i < MCELLS; i += HT) lh[i] = 0u;
    __syncthreads();

    const int wave = tid >> 6;
    const bool use_lds = (wave < 2);            // waves 0,1 -> LDS pipe
    unsigned* __restrict__ gcopy =              // waves 2,3 -> global pipe
        ghist + (size_t)((((unsigned)blockIdx.x << 1) | (wave & 1)) & (NCOPIES - 1)) * MCELLS;

    const int n4 = n >> 2;
    const float4* __restrict__ x4 = (const float4*)x;
    const int stride = HB * (HT * 2);
    // cell f = floor((t+5)*32) = floor(x*512 + 1184)
    for (int i0 = blockIdx.x * (HT * 2) + tid; i0 < n4; i0 += stride) {
        const int i1 = i0 + HT;
        const bool ok1 = (i1 < n4);
        float4 a = x4[i0];
        float4 b = ok1 ? x4[i1] : make_float4(0.f, 0.f, 0.f, 0.f);

        int f0 = min(max((int)floorf(fmaf(a.x, 512.0f, 1184.0f)), 0), MCELLS - 1);
        int f1 = min(max((int)floorf(fmaf(a.y, 512.0f, 1184.0f)), 0), MCELLS - 1);
        int f2 = min(max((int)floorf(fmaf(a.z, 512.0f, 1184.0f)), 0), MCELLS - 1);
        int f3 = min(max((int)floorf(fmaf(a.w, 512.0f, 1184.0f)), 0), MCELLS - 1);
        if (use_lds) {
            atomicAdd(&lh[f0], 1u); atomicAdd(&lh[f1], 1u);
            atomicAdd(&lh[f2], 1u); atomicAdd(&lh[f3], 1u);
        } else {
            atomicAdd(&gcopy[f0], 1u); atomicAdd(&gcopy[f1], 1u);
            atomicAdd(&gcopy[f2], 1u); atomicAdd(&gcopy[f3], 1u);
        }
        if (ok1) {
            int g0 = min(max((int)floorf(fmaf(b.x, 512.0f, 1184.0f)), 0), MCELLS - 1);
            int g1 = min(max((int)floorf(fmaf(b.y, 512.0f, 1184.0f)), 0), MCELLS - 1);
            int g2 = min(max((int)floorf(fmaf(b.z, 512.0f, 1184.0f)), 0), MCELLS - 1);
            int g3 = min(max((int)floorf(fmaf(b.w, 512.0f, 1184.0f)), 0), MCELLS - 1);
            if (use_lds) {
                atomicAdd(&lh[g0], 1u); atomicAdd(&lh[g1], 1u);
                atomicAdd(&lh[g2], 1u); atomicAdd(&lh[g3], 1u);
            } else {
                atomicAdd(&gcopy[g0], 1u); atomicAdd(&gcopy[g1], 1u);
                atomicAdd(&gcopy[g2], 1u); atomicAdd(&gcopy[g3], 1u);
            }
        }
    }
    if (blockIdx.x == 0) {                      // scalar tail (n%4), defensive
        int tail = n & 3;
        if (tid < tail) {
            float v = x[(n >> 2) * 4 + tid];
            int f = min(max((int)floorf(fmaf(v, 512.0f, 1184.0f)), 0), MCELLS - 1);
            atomicAdd(&ghist[f], 1u);           // copy 0
        }
    }
    __syncthreads();

    // flush LDS histogram into a global copy (sparse: skip empty cells)
    unsigned* __restrict__ fc =
        ghist + (size_t)(blockIdx.x & (NCOPIES - 1)) * MCELLS;
    for (int i = tid; i < MCELLS; i += HT) {
        unsigned v = lh[i];
        if (v) atomicAdd(&fc[i], v);
    }
}

__global__ void __launch_bounds__(256)
collapse_kernel(const unsigned* __restrict__ ghist, unsigned* __restrict__ coll)
{
    int m = blockIdx.x * 256 + threadIdx.x;
    if (m >= MCELLS) return;
    unsigned s = 0;
    #pragma unroll 8
    for (int c = 0; c < NCOPIES; ++c) s += ghist[(size_t)c * MCELLS + m];
    coll[m] = s;
}

__global__ void __launch_bounds__(256)
window_kernel(const unsigned* __restrict__ coll, float* __restrict__ out, float invN)
{
    const int b   = blockIdx.x;                 // one block per output bin
    const int tid = threadIdx.x;
    const int limit = b << DLOG;                // cells below the window: weight 1
    float acc = 0.0f;
    for (int m = tid; m < limit; m += 256) acc += (float)coll[m];

    const float zc = 4.0f * (float)b + 19.9375f;  // z = 4b + 20 - (m+0.5)/8
    #pragma unroll
    for (int k = 0; k < 2; ++k) {               // 320-cell sigmoid window
        int m = limit + (k << 8) + tid;
        if (m < limit + (10 << DLOG)) {
            float z = fmaf((float)m, -0.125f, zc);
            float s = 1.0f / (1.0f + __expf(-z));
            acc = fmaf((float)coll[m], s, acc);
        }
    }
    __shared__ double sd[256];
    sd[tid] = (double)acc;
    __syncthreads();
    for (int o = 128; o > 0; o >>= 1) {
        if (tid < o) sd[tid] += sd[tid + o];
        __syncthreads();
    }
    if (tid == 0) out[b] = (float)(sd[0] * (double)invN);
}

extern "C" void kernel_launch(void* const* d_in, const int* in_sizes, int n_in,
                              void* d_out, int out_size, void* d_ws, size_t ws_size,
                              hipStream_t stream)
{
    const float* x = (const float*)d_in[0];
    const int n = in_sizes[0];
    unsigned* ghist = (unsigned*)d_ws;                      // 2.42 MB
    unsigned* coll  = ghist + (size_t)NCOPIES * MCELLS;     // 9.5 KB

    hipMemsetAsync(ghist, 0, (size_t)NCOPIES * MCELLS * sizeof(unsigned), stream);
    hist_kernel<<<HB, HT, 0, stream>>>(x, ghist, n);
    collapse_kernel<<<(MCELLS + 255) / 256, 256, 0, stream>>>(ghist, coll);
    window_kernel<<<64, 256, 0, stream>>>(coll, (float*)d_out, 1.0f / (float)n);
}

// Round 6
// 372.984 us; speedup vs baseline: 3.5463x; 3.5463x over previous
//
#include <hip/hip_runtime.h>
#include <hip/hip_bf16.h>

// out[b] = mean_x( 0.5 - 0.5*tanh((x - bins[b]) * 2/bw) ), bw = 0.0625,
//          bins[b] = -2 + bw*b, b in [0,64)
// t = (x+2)*16; element contribution to bin b = sigma(4(b-t)), saturating to
// {0,1} for |b-t| >= 5. Fine histogram of t (cell = 1/8 bin, t in [-5,69),
// 592 cells) is a sufficient statistic (quantization bias ~3e-4 << 1.9e-2).
//
// Measured structure (R2-R5): scattered LDS atomics retire ~1 lane/cycle/CU
// (67.1M atomics = 109 us; grid/unroll-insensitive). Global scattered atomics
// are ~30x worse (R5: write-through, ~30 ns each). VALU direct-eval of 64
// bins costs ~0.25 elem/cyc/CU -- slower than the atomic pipe. So the hist
// kernel floor is the LDS atomic pipe at ~109 us; HBM (43 us) hides under it.
// This version = R2 structure at that floor with minimized aux cost.

#define DLOG  3
#define CELLS 592               // 74 * 8 cells, t in [-5, 69)
#define HB 2048
#define HT 256

__global__ void __launch_bounds__(HT)
hist_kernel(const float* __restrict__ x, unsigned* __restrict__ ghist, int n)
{
    __shared__ unsigned lh[2][CELLS];          // 4.7 KB; copy per wave-parity
    const int tid = threadIdx.x;
    for (int i = tid; i < 2 * CELLS; i += HT) ((unsigned*)lh)[i] = 0u;
    __syncthreads();

    unsigned* __restrict__ myh = lh[(tid >> 6) & 1];

    const int n4 = n >> 2;
    const float4* __restrict__ x4 = (const float4*)x;
    const int stride = HB * HT;
    // cell f = floor((t+5)*8) = floor(x*128 + 296)   -- one FMA per element
    for (int i = blockIdx.x * HT + tid; i < n4; i += stride) {
        float4 v = x4[i];
        int f0 = (int)floorf(fmaf(v.x, 128.0f, 296.0f));
        int f1 = (int)floorf(fmaf(v.y, 128.0f, 296.0f));
        int f2 = (int)floorf(fmaf(v.z, 128.0f, 296.0f));
        int f3 = (int)floorf(fmaf(v.w, 128.0f, 296.0f));
        f0 = min(max(f0, 0), CELLS - 1);
        f1 = min(max(f1, 0), CELLS - 1);
        f2 = min(max(f2, 0), CELLS - 1);
        f3 = min(max(f3, 0), CELLS - 1);
        atomicAdd(&myh[f0], 1u);
        atomicAdd(&myh[f1], 1u);
        atomicAdd(&myh[f2], 1u);
        atomicAdd(&myh[f3], 1u);
    }
    if (blockIdx.x == 0) {                     // scalar tail (n%4), defensive
        int tail = n & 3;
        if (tid < tail) {
            float v = x[(n & ~3) + tid];
            int f = min(max((int)floorf(fmaf(v, 128.0f, 296.0f)), 0), CELLS - 1);
            atomicAdd(&lh[0][f], 1u);
        }
    }
    __syncthreads();

    // flush: 592 global atomics/block, start staggered per block to spread
    // same-line pressure across the 148 cache lines
    const int rot = (blockIdx.x & 31) * 16;
    for (int i = tid; i < CELLS; i += HT) {
        int c = i + rot; if (c >= CELLS) c -= CELLS;
        unsigned v = lh[0][c] + lh[1][c];
        if (v) atomicAdd(&ghist[c], v);
    }
}

__global__ void __launch_bounds__(64)
window_kernel(const unsigned* __restrict__ ghist, float* __restrict__ out,
              float invN)
{
    const int b = blockIdx.x;                  // one wave per output bin
    const int lane = threadIdx.x;
    const int limit = b << DLOG;               // cells below window: weight 1

    unsigned ci = 0u;
    for (int f = lane; f < limit; f += 64) ci += ghist[f];

    float cf = 0.0f;
    const int hi = min(limit + (10 << DLOG), CELLS);
    for (int f = limit + lane; f < hi; f += 64) {
        float t = fmaf((float)f, 0.125f, -4.9375f);   // cell center
        float z = 4.0f * ((float)b - t);
        float s = 1.0f / (1.0f + __expf(-z));
        cf = fmaf((float)ghist[f], s, cf);
    }
    float acc = (float)ci + cf;
    #pragma unroll
    for (int m = 32; m > 0; m >>= 1) acc += __shfl_xor(acc, m, 64);
    if (lane == 0) out[b] = (float)((double)acc * (double)invN);
}

extern "C" void kernel_launch(void* const* d_in, const int* in_sizes, int n_in,
                              void* d_out, int out_size, void* d_ws, size_t ws_size,
                              hipStream_t stream)
{
    const float* x = (const float*)d_in[0];
    const int n = in_sizes[0];
    unsigned* ghist = (unsigned*)d_ws;         // 2.4 KB

    hipMemsetAsync(ghist, 0, CELLS * sizeof(unsigned), stream);
    hist_kernel<<<HB, HT, 0, stream>>>(x, ghist, n);
    window_kernel<<<64, 64, 0, stream>>>(ghist, (float*)d_out, 1.0f / (float)n);
}